// Round 10
// baseline (568.930 us; speedup 1.0000x reference)
//
#include <hip/hip_runtime.h>
#include <stdint.h>

#define N_NODES 100000
#define N_EDGES 1600000
#define D 128
#define NBUCK 196          // ceil(N_NODES/512); bucket b = dst >> 9
#define BSTRIDE 9216       // fixed pairs region per bucket (mean 8163, +11 sigma)
#define PCHUNK 2048        // edges per k_part block (16KB x2 LDS -> 4 blocks/CU)
#define QTILE 32           // nodes per fused block
#define NTILE (N_NODES / QTILE)   // 3125 exact
#define CASTB 3125         // 512-thread cast blocks: 3125*512*8 = 12.8M floats exact
#define WPACKB 128         // 128*512 = 65536 weight elements (both layers)
#define DBINS 64           // degree histogram bins (deg clamped to 63)
#define ORDB 98            // order-scatter blocks: 98*1024 >= 100000

typedef unsigned int uint32;
typedef __attribute__((ext_vector_type(8))) short short8;   // 8 bf16 = 4 VGPRs
typedef __attribute__((ext_vector_type(4))) float f32x4;

__device__ __forceinline__ unsigned short f2bf(float f) {
  unsigned u = __builtin_bit_cast(unsigned, f);
  u += 0x7fffu + ((u >> 16) & 1u);          // round-to-nearest-even
  return (unsigned short)(u >> 16);
}
__device__ __forceinline__ float bflo(unsigned v) {
  return __builtin_bit_cast(float, v << 16);
}
__device__ __forceinline__ float bfhi(unsigned v) {
  return __builtin_bit_cast(float, v & 0xffff0000u);
}

// ---------------- CSR build (2 passes over edges) ------
// r3 lesson: no per-edge global atomic scatter (15x write amplification).
// r0/r7 lesson: no segmented-accumulate branches inside gather loops.
// r9 lesson: no hand-staged register arrays inside runtime loops (scratch spill).

__global__ __launch_bounds__(256) void k_part(const int* __restrict__ src,
                                              const int* __restrict__ dst,
                                              int* __restrict__ bcnt,
                                              uint2* __restrict__ pairs) {
  __shared__ uint2 buff[PCHUNK];     // 16 KB
  __shared__ uint2 sorted[PCHUNK];   // 16 KB
  __shared__ int hist[256], stmp[256], loff[256], cpos[256], base[256];
  int tid = threadIdx.x;
  int e0 = blockIdx.x * PCHUNK;
  int nv = N_EDGES - e0;
  if (nv > PCHUNK) nv = PCHUNK;

  hist[tid] = 0;
  __syncthreads();
  for (int i = tid; i < nv; i += 256) {
    int d = dst[e0 + i];
    int s = src[e0 + i];
    buff[i] = make_uint2((uint32)d, (uint32)s);
    atomicAdd(&hist[d >> 9], 1);
  }
  __syncthreads();
  int v = hist[tid];
  stmp[tid] = v;
  __syncthreads();
  for (int off = 1; off < 256; off <<= 1) {
    int t = (tid >= off) ? stmp[tid - off] : 0;
    __syncthreads();
    stmp[tid] += t;
    __syncthreads();
  }
  loff[tid] = stmp[tid] - v;
  cpos[tid] = stmp[tid] - v;
  base[tid] = (v > 0) ? atomicAdd(&bcnt[tid], v) : 0;   // reserve run in bucket region
  __syncthreads();
  for (int i = tid; i < nv; i += 256) {
    uint2 p = buff[i];
    int r = atomicAdd(&cpos[p.x >> 9], 1);
    sorted[r] = p;
  }
  __syncthreads();
  for (int i = tid; i < nv; i += 256) {
    uint2 p = sorted[i];
    int b = (int)(p.x >> 9);
    int local = base[b] + (i - loff[b]);
    if (local < BSTRIDE)                                // det. input: never trips
      pairs[(size_t)b * BSTRIDE + local] = p;
  }
}

// Merged dispatch: blocks [0,NBUCK) build per-bucket rowptr+csr AND feed the
// global degree histogram (per-node degree = LDS hist value, already computed);
// remaining blocks do x-cast + W-pack on the CUs the 196 csr blocks leave idle.
__global__ __launch_bounds__(512) void k_csr_prep(
    const uint2* __restrict__ pairs, const int* __restrict__ bcnt,
    int* __restrict__ rowptr, int* __restrict__ csr, int* __restrict__ dhist,
    const float* __restrict__ x, unsigned short* __restrict__ xb,
    const float* __restrict__ Wl1, const float* __restrict__ Wr1,
    const float* __restrict__ Wl2, const float* __restrict__ Wr2,
    unsigned short* __restrict__ Wp1, unsigned short* __restrict__ Wp2) {
  __shared__ int hist[512], off[512], cur[512], scn[512], dh[DBINS];
  int tid = threadIdx.x;
  int blk = blockIdx.x;

  if (blk >= NBUCK) {
    int pb = blk - NBUCK;
    if (pb < CASTB) {                     // x f32 -> bf16, 8 elems/thread
      size_t i = (size_t)pb * 512 + tid;  // < 1.6M exact
      float4 a = *reinterpret_cast<const float4*>(x + i * 8);
      float4 c = *reinterpret_cast<const float4*>(x + i * 8 + 4);
      uint4 o;
      o.x = (uint32)f2bf(a.x) | ((uint32)f2bf(a.y) << 16);
      o.y = (uint32)f2bf(a.z) | ((uint32)f2bf(a.w) << 16);
      o.z = (uint32)f2bf(c.x) | ((uint32)f2bf(c.y) << 16);
      o.w = (uint32)f2bf(c.z) | ((uint32)f2bf(c.w) << 16);
      *reinterpret_cast<uint4*>(xb + i * 8) = o;
    } else {                              // pack both layers' W into B-frag order
      int t = (pb - CASTB) * 512 + tid;   // < 65536 exact
      int which = t >> 15;
      int tt = t & 32767;
      int j = tt & 7;
      int lane = (tt >> 3) & 63;
      int tile = (tt >> 9) & 1;
      int ks = (tt >> 10) & 7;
      int ng = (tt >> 13) & 3;
      int k = ks * 32 + (lane >> 4) * 8 + j;
      int n = ng * 32 + tile * 16 + (lane & 15);
      const float* Wl = which ? Wl2 : Wl1;
      const float* Wr = which ? Wr2 : Wr1;
      float w = (k < 128) ? Wl[k * 128 + n] : Wr[(k - 128) * 128 + n];
      (which ? Wp2 : Wp1)[tt] = f2bf(w);
    }
    return;
  }

  int b = blk;
  // inclusive scan of bucket counts -> bucket base for this block
  int bv = (tid < NBUCK) ? bcnt[tid] : 0;
  scn[tid] = bv;
  __syncthreads();
  for (int o = 1; o < 512; o <<= 1) {
    int t = (tid >= o) ? scn[tid - o] : 0;
    __syncthreads();
    scn[tid] += t;
    __syncthreads();
  }
  int bb = (b == 0) ? 0 : scn[b - 1];
  if (b == NBUCK - 1 && tid == 0) rowptr[N_NODES] = scn[NBUCK - 1];

  int lo = b << 9;
  int hi = lo + 512;
  if (hi > N_NODES) hi = N_NODES;
  int ne = bcnt[b];
  if (ne > BSTRIDE) ne = BSTRIDE;
  const uint2* pb2 = pairs + (size_t)b * BSTRIDE;

  hist[tid] = 0;
  if (tid < DBINS) dh[tid] = 0;
  __syncthreads();
  for (int i = tid; i < ne; i += 512) atomicAdd(&hist[(int)pb2[i].x - lo], 1);
  __syncthreads();
  int v = hist[tid];
  off[tid] = v;
  __syncthreads();
  for (int o = 1; o < 512; o <<= 1) {
    int t = (tid >= o) ? off[tid - o] : 0;
    __syncthreads();
    off[tid] += t;
    __syncthreads();
  }
  off[tid] -= v;               // exclusive
  cur[tid] = off[tid];
  if (lo + tid < hi) {
    rowptr[lo + tid] = bb + off[tid];
    atomicAdd(&dh[v > 63 ? 63 : v], 1);   // per-node degree into local bins
  }
  __syncthreads();
  if (tid < DBINS && dh[tid]) atomicAdd(&dhist[tid], dh[tid]);
  for (int i = tid; i < ne; i += 512) {
    int d = (int)pb2[i].x - lo;
    int slot = atomicAdd(&cur[d], 1);
    csr[bb + slot] = (int)pb2[i].y;
  }
}

// exclusive scan of 64 degree bins -> running bases for the order scatter
__global__ void k_dscan(const int* __restrict__ dhist, int* __restrict__ dbase) {
  __shared__ int s[DBINS];
  int t = threadIdx.x;     // 64
  int v = dhist[t];
  s[t] = v;
  __syncthreads();
  for (int o = 1; o < DBINS; o <<= 1) {
    int x = (t >= o) ? s[t - o] : 0;
    __syncthreads();
    s[t] += x;
    __syncthreads();
  }
  dbase[t] = s[t] - v;     // exclusive
}

// scatter node ids into degree-sorted order (counting sort, 64 bins)
__global__ __launch_bounds__(1024) void k_dorder(const int* __restrict__ rowptr,
                                                 int* __restrict__ dbase,
                                                 int* __restrict__ order) {
  int n = blockIdx.x * 1024 + threadIdx.x;
  if (n >= N_NODES) return;
  int deg = rowptr[n + 1] - rowptr[n];
  if (deg > 63) deg = 63;
  int slot = atomicAdd(&dbase[deg], 1);
  order[slot] = n;
}

// ---------------- fused mean-aggregate + GEMM, degree-sorted tiles ----------
// Identical to the verified r6 kernel (88.5us, 44 VGPR, no spill) except each
// block's 32 nodes come from order[] (degree-adjacent) -> barrier waits on
// max degree ~= mean degree (r6's fixed tiles paid E[max32 Poi16]/16 = 1.55x,
// measured 88.5/57.2 = 1.55). Gather loop byte-identical to proven 57.2us.

#define ACC8(v)                                          \
  acc[0] += bflo(v.x); acc[1] += bfhi(v.x);              \
  acc[2] += bflo(v.y); acc[3] += bfhi(v.y);              \
  acc[4] += bflo(v.z); acc[5] += bfhi(v.z);              \
  acc[6] += bflo(v.w); acc[7] += bfhi(v.w);

__global__ __launch_bounds__(512, 4) void k_fused(
    const unsigned short* __restrict__ table,   // gather table AND x-half rows
    const int* __restrict__ rowptr, const int* __restrict__ csr,
    const int* __restrict__ order,
    const unsigned short* __restrict__ Wp, const float* __restrict__ bias,
    void* __restrict__ outp, int relu_bf16_out) {
  __shared__ unsigned short meanB[QTILE * 128];   // 8 KB, XOR-swizzled 16B groups
  int tid = threadIdx.x;
  int g = tid >> 4;          // node slot 0..31 within tile
  int l = tid & 15;          // 16B lane within row
  int n0 = blockIdx.x * QTILE;
  int node = order[n0 + g];  // degree-sorted indirection (uniform per group)

  // ---- phase 1: mean of in-neighbors (r4/r6 exact inner loop) ----
  int beg = rowptr[node], end = rowptr[node + 1];
  float acc[8] = {0.f, 0.f, 0.f, 0.f, 0.f, 0.f, 0.f, 0.f};
  int e = beg;
  for (; e + 8 <= end; e += 8) {     // 8 gathers in flight
    int s0 = csr[e], s1 = csr[e + 1], s2 = csr[e + 2], s3 = csr[e + 3];
    int s4 = csr[e + 4], s5 = csr[e + 5], s6 = csr[e + 6], s7 = csr[e + 7];
    uint4 v0 = *reinterpret_cast<const uint4*>(table + (size_t)s0 * D + l * 8);
    uint4 v1 = *reinterpret_cast<const uint4*>(table + (size_t)s1 * D + l * 8);
    uint4 v2 = *reinterpret_cast<const uint4*>(table + (size_t)s2 * D + l * 8);
    uint4 v3 = *reinterpret_cast<const uint4*>(table + (size_t)s3 * D + l * 8);
    uint4 v4 = *reinterpret_cast<const uint4*>(table + (size_t)s4 * D + l * 8);
    uint4 v5 = *reinterpret_cast<const uint4*>(table + (size_t)s5 * D + l * 8);
    uint4 v6 = *reinterpret_cast<const uint4*>(table + (size_t)s6 * D + l * 8);
    uint4 v7 = *reinterpret_cast<const uint4*>(table + (size_t)s7 * D + l * 8);
    ACC8(v0) ACC8(v1) ACC8(v2) ACC8(v3)
    ACC8(v4) ACC8(v5) ACC8(v6) ACC8(v7)
  }
  for (; e + 4 <= end; e += 4) {
    int s0 = csr[e], s1 = csr[e + 1], s2 = csr[e + 2], s3 = csr[e + 3];
    uint4 v0 = *reinterpret_cast<const uint4*>(table + (size_t)s0 * D + l * 8);
    uint4 v1 = *reinterpret_cast<const uint4*>(table + (size_t)s1 * D + l * 8);
    uint4 v2 = *reinterpret_cast<const uint4*>(table + (size_t)s2 * D + l * 8);
    uint4 v3 = *reinterpret_cast<const uint4*>(table + (size_t)s3 * D + l * 8);
    ACC8(v0) ACC8(v1) ACC8(v2) ACC8(v3)
  }
  for (; e < end; ++e) {
    int s0 = csr[e];
    uint4 v0 = *reinterpret_cast<const uint4*>(table + (size_t)s0 * D + l * 8);
    ACC8(v0)
  }
  float inv = (end > beg) ? 1.0f / (float)(end - beg) : 0.0f;
  uint4 o;
  o.x = (uint32)f2bf(acc[0] * inv) | ((uint32)f2bf(acc[1] * inv) << 16);
  o.y = (uint32)f2bf(acc[2] * inv) | ((uint32)f2bf(acc[3] * inv) << 16);
  o.z = (uint32)f2bf(acc[4] * inv) | ((uint32)f2bf(acc[5] * inv) << 16);
  o.w = (uint32)f2bf(acc[6] * inv) | ((uint32)f2bf(acc[7] * inv) << 16);
  // swizzled store: content-group l -> slot l^(g&15)  (bank-spread reads)
  *reinterpret_cast<uint4*>(&meanB[g * 128 + (l ^ (g & 15)) * 8]) = o;
  __syncthreads();

  // ---- phase 2: [mean | x] @ Wp (r6's verified mapping; rows via order[]) ----
  int wave = tid >> 6;       // 8 waves: wr = row-half, wc = col-quarter
  int lane = tid & 63;
  int wr = wave >> 2;
  int wc = wave & 3;
  int q = lane >> 4;
  int r = lane & 15;

  short8 Bf[8][2];           // registers live only in phase 2
  const unsigned short* wp = Wp + (size_t)wc * 8192 + lane * 8;
#pragma unroll
  for (int ks = 0; ks < 8; ++ks)
#pragma unroll
    for (int t = 0; t < 2; ++t)
      Bf[ks][t] = *reinterpret_cast<const short8*>(wp + (ks * 2 + t) * 512);

  int arow = wr * 16 + r;    // A row slot within tile
  int an = order[n0 + arow]; // its node id
  short8 A[8];
  const unsigned short* ax = table + (size_t)an * D + q * 8;
#pragma unroll
  for (int ks = 0; ks < 4; ++ks)
    A[4 + ks] = *reinterpret_cast<const short8*>(ax + ks * 32);
#pragma unroll
  for (int ks = 0; ks < 4; ++ks) {   // mean half: slot = group ^ (row&15)
    int slot = (ks * 4 + q) ^ r;
    A[ks] = *reinterpret_cast<const short8*>(&meanB[arow * 128 + slot * 8]);
  }

  f32x4 c0 = {0.f, 0.f, 0.f, 0.f}, c1 = {0.f, 0.f, 0.f, 0.f};
#pragma unroll
  for (int ks = 0; ks < 8; ++ks) {
    c0 = __builtin_amdgcn_mfma_f32_16x16x32_bf16(A[ks], Bf[ks][0], c0, 0, 0, 0);
    c1 = __builtin_amdgcn_mfma_f32_16x16x32_bf16(A[ks], Bf[ks][1], c1, 0, 0, 0);
  }

  float bia0 = bias[wc * 32 + r];
  float bia1 = bias[wc * 32 + 16 + r];
  // C: col=lane&15, row(slot)=wr*16+q*4+gg -> node order[n0+slot] (row scatter)
  if (relu_bf16_out) {
#pragma unroll
    for (int gg = 0; gg < 4; ++gg) {
      int on = order[n0 + wr * 16 + q * 4 + gg];
      unsigned short* ob = (unsigned short*)outp + (size_t)on * D + wc * 32 + r;
      ob[0] = f2bf(fmaxf(c0[gg] + bia0, 0.f));
      ob[16] = f2bf(fmaxf(c1[gg] + bia1, 0.f));
    }
  } else {
#pragma unroll
    for (int gg = 0; gg < 4; ++gg) {
      int on = order[n0 + wr * 16 + q * 4 + gg];
      float* of = (float*)outp + (size_t)on * D + wc * 32 + r;
      of[0] = c0[gg] + bia0;
      of[16] = c1[gg] + bia1;
    }
  }
}

// ---------------- launch ----------------

extern "C" void kernel_launch(void* const* d_in, const int* in_sizes, int n_in,
                              void* d_out, int out_size, void* d_ws, size_t ws_size,
                              hipStream_t stream) {
  const float* x   = (const float*)d_in[0];
  const int*   ei  = (const int*)d_in[1];
  const float* Wl1 = (const float*)d_in[2];
  const float* Wr1 = (const float*)d_in[3];
  const float* b1  = (const float*)d_in[4];
  const float* Wl2 = (const float*)d_in[5];
  const float* Wr2 = (const float*)d_in[6];
  const float* b2  = (const float*)d_in[7];
  float* out = (float*)d_out;

  const int* esrc = ei;
  const int* edst = ei + N_EDGES;

  char* p = (char*)d_ws;
  auto take = [&](size_t bytes) {
    char* q = p;
    p += (bytes + 255) & ~(size_t)255;
    return q;
  };
  int* ctrl   = (int*)take((256 + DBINS + DBINS) * 4);   // bcnt | dhist | dbase
  int* bcnt   = ctrl;
  int* dhist  = ctrl + 256;
  int* dbase  = ctrl + 256 + DBINS;
  int* rowptr = (int*)take((size_t)(N_NODES + 1) * 4);
  int* csr    = (int*)take((size_t)N_EDGES * 4);
  int* order  = (int*)take((size_t)N_NODES * 4);
  uint2* pairs = (uint2*)take((size_t)NBUCK * BSTRIDE * 8);   // 14.5 MB
  unsigned short* xb  = (unsigned short*)take((size_t)N_NODES * D * 2);
  unsigned short* hb  = (unsigned short*)take((size_t)N_NODES * D * 2);
  unsigned short* Wp1 = (unsigned short*)take(256 * 128 * 2);
  unsigned short* Wp2 = (unsigned short*)take(256 * 128 * 2);

  const int npart = (N_EDGES + PCHUNK - 1) / PCHUNK;   // 782

  // CSR build: partition -> (per-bucket rowptr+csr+deg-hist || prep on idle CUs)
  hipMemsetAsync(ctrl, 0, (256 + DBINS + DBINS) * 4, stream);
  k_part<<<npart, 256, 0, stream>>>(esrc, edst, bcnt, pairs);
  k_csr_prep<<<NBUCK + CASTB + WPACKB, 512, 0, stream>>>(
      pairs, bcnt, rowptr, csr, dhist, x, xb, Wl1, Wr1, Wl2, Wr2, Wp1, Wp2);
  // degree-sorted node order (counting sort, 64 bins)
  k_dscan<<<1, DBINS, 0, stream>>>(dhist, dbase);
  k_dorder<<<ORDB, 1024, 0, stream>>>(rowptr, dbase, order);

  // layer 1: hb = relu([mean(xb)|xb] @ Wp1 + b1)   (bf16 out)
  k_fused<<<NTILE, 512, 0, stream>>>(xb, rowptr, csr, order, Wp1, b1, hb, 1);
  // layer 2: out = [mean(hb)|hb] @ Wp2 + b2        (f32 out)
  k_fused<<<NTILE, 512, 0, stream>>>(hb, rowptr, csr, order, Wp2, b2, out, 0);
}

// Round 11
// 329.697 us; speedup vs baseline: 1.7256x; 1.7256x over previous
//
#include <hip/hip_runtime.h>
#include <stdint.h>

#define N_NODES 100000
#define N_EDGES 1600000
#define D 128
#define NBUCK 196          // ceil(N_NODES/512); bucket b = dst >> 9
#define BSTRIDE 9216       // fixed pairs region per bucket (mean 8163, +11 sigma)
#define PCHUNK 2048        // edges per k_part block (16KB x2 LDS -> 4 blocks/CU)
#define QTILE 32           // nodes per fused block
#define NTILE (N_NODES / QTILE)   // 3125 exact
#define CASTB 3125         // 512-thread cast blocks: 3125*512*8 = 12.8M floats exact
#define WPACKB 128         // 128*512 = 65536 weight elements (both layers)
#define DBINS 64           // degree bins for bucket-local counting sort

typedef unsigned int uint32;
typedef __attribute__((ext_vector_type(8))) short short8;   // 8 bf16 = 4 VGPRs
typedef __attribute__((ext_vector_type(4))) float f32x4;

__device__ __forceinline__ unsigned short f2bf(float f) {
  unsigned u = __builtin_bit_cast(unsigned, f);
  u += 0x7fffu + ((u >> 16) & 1u);          // round-to-nearest-even
  return (unsigned short)(u >> 16);
}
__device__ __forceinline__ float bflo(unsigned v) {
  return __builtin_bit_cast(float, v << 16);
}
__device__ __forceinline__ float bfhi(unsigned v) {
  return __builtin_bit_cast(float, v & 0xffff0000u);
}

// ---------------- CSR build (2 passes over edges) ------
// r3 lesson: no per-edge global atomic scatter (15x write amplification).
// r0/r7 lesson: no segmented-accumulate branches inside gather loops.
// r9 lesson: no hand-staged register arrays inside runtime loops (spill).
// r10 lesson: no contended GLOBAL atomic counters (k_dorder: 100K atomics
// over 64 words = 264us, lines ping-pong across 8 XCD L2s). LDS only.

__global__ __launch_bounds__(256) void k_part(const int* __restrict__ src,
                                              const int* __restrict__ dst,
                                              int* __restrict__ bcnt,
                                              uint2* __restrict__ pairs) {
  __shared__ uint2 buff[PCHUNK];     // 16 KB
  __shared__ uint2 sorted[PCHUNK];   // 16 KB
  __shared__ int hist[256], stmp[256], loff[256], cpos[256], base[256];
  int tid = threadIdx.x;
  int e0 = blockIdx.x * PCHUNK;
  int nv = N_EDGES - e0;
  if (nv > PCHUNK) nv = PCHUNK;

  hist[tid] = 0;
  __syncthreads();
  for (int i = tid; i < nv; i += 256) {
    int d = dst[e0 + i];
    int s = src[e0 + i];
    buff[i] = make_uint2((uint32)d, (uint32)s);
    atomicAdd(&hist[d >> 9], 1);
  }
  __syncthreads();
  int v = hist[tid];
  stmp[tid] = v;
  __syncthreads();
  for (int off = 1; off < 256; off <<= 1) {
    int t = (tid >= off) ? stmp[tid - off] : 0;
    __syncthreads();
    stmp[tid] += t;
    __syncthreads();
  }
  loff[tid] = stmp[tid] - v;
  cpos[tid] = stmp[tid] - v;
  base[tid] = (v > 0) ? atomicAdd(&bcnt[tid], v) : 0;   // reserve run in bucket region
  __syncthreads();
  for (int i = tid; i < nv; i += 256) {
    uint2 p = buff[i];
    int r = atomicAdd(&cpos[p.x >> 9], 1);
    sorted[r] = p;
  }
  __syncthreads();
  for (int i = tid; i < nv; i += 256) {
    uint2 p = sorted[i];
    int b = (int)(p.x >> 9);
    int local = base[b] + (i - loff[b]);
    if (local < BSTRIDE)                                // det. input: never trips
      pairs[(size_t)b * BSTRIDE + local] = p;
  }
}

// Merged dispatch: blocks [0,NBUCK) build per-bucket rowptr+csr AND a
// bucket-local degree-sorted order[] (LDS counting sort, 64 bins — the node
// degrees already sit in this block's LDS histogram). Buckets hold 512 or 160
// nodes, both multiples of 32, so 32-node fused tiles never straddle buckets.
// Remaining blocks do x-cast + W-pack on the CUs the 196 csr blocks leave idle.
__global__ __launch_bounds__(512) void k_csr_prep(
    const uint2* __restrict__ pairs, const int* __restrict__ bcnt,
    int* __restrict__ rowptr, int* __restrict__ csr, int* __restrict__ order,
    const float* __restrict__ x, unsigned short* __restrict__ xb,
    const float* __restrict__ Wl1, const float* __restrict__ Wr1,
    const float* __restrict__ Wl2, const float* __restrict__ Wr2,
    unsigned short* __restrict__ Wp1, unsigned short* __restrict__ Wp2) {
  __shared__ int hist[512], off[512], cur[512], scn[512], dh[DBINS];
  int tid = threadIdx.x;
  int blk = blockIdx.x;

  if (blk >= NBUCK) {
    int pb = blk - NBUCK;
    if (pb < CASTB) {                     // x f32 -> bf16, 8 elems/thread
      size_t i = (size_t)pb * 512 + tid;  // < 1.6M exact
      float4 a = *reinterpret_cast<const float4*>(x + i * 8);
      float4 c = *reinterpret_cast<const float4*>(x + i * 8 + 4);
      uint4 o;
      o.x = (uint32)f2bf(a.x) | ((uint32)f2bf(a.y) << 16);
      o.y = (uint32)f2bf(a.z) | ((uint32)f2bf(a.w) << 16);
      o.z = (uint32)f2bf(c.x) | ((uint32)f2bf(c.y) << 16);
      o.w = (uint32)f2bf(c.z) | ((uint32)f2bf(c.w) << 16);
      *reinterpret_cast<uint4*>(xb + i * 8) = o;
    } else {                              // pack both layers' W into B-frag order
      int t = (pb - CASTB) * 512 + tid;   // < 65536 exact
      int which = t >> 15;
      int tt = t & 32767;
      int j = tt & 7;
      int lane = (tt >> 3) & 63;
      int tile = (tt >> 9) & 1;
      int ks = (tt >> 10) & 7;
      int ng = (tt >> 13) & 3;
      int k = ks * 32 + (lane >> 4) * 8 + j;
      int n = ng * 32 + tile * 16 + (lane & 15);
      const float* Wl = which ? Wl2 : Wl1;
      const float* Wr = which ? Wr2 : Wr1;
      float w = (k < 128) ? Wl[k * 128 + n] : Wr[(k - 128) * 128 + n];
      (which ? Wp2 : Wp1)[tt] = f2bf(w);
    }
    return;
  }

  int b = blk;
  // inclusive scan of bucket counts -> bucket base for this block
  int bv = (tid < NBUCK) ? bcnt[tid] : 0;
  scn[tid] = bv;
  __syncthreads();
  for (int o = 1; o < 512; o <<= 1) {
    int t = (tid >= o) ? scn[tid - o] : 0;
    __syncthreads();
    scn[tid] += t;
    __syncthreads();
  }
  int bb = (b == 0) ? 0 : scn[b - 1];
  if (b == NBUCK - 1 && tid == 0) rowptr[N_NODES] = scn[NBUCK - 1];

  int lo = b << 9;
  int hi = lo + 512;
  if (hi > N_NODES) hi = N_NODES;
  int nn = hi - lo;            // 512 or 160 (both multiples of 32)
  int ne = bcnt[b];
  if (ne > BSTRIDE) ne = BSTRIDE;
  const uint2* pb2 = pairs + (size_t)b * BSTRIDE;

  hist[tid] = 0;
  __syncthreads();
  for (int i = tid; i < ne; i += 512) atomicAdd(&hist[(int)pb2[i].x - lo], 1);
  __syncthreads();
  int v = hist[tid];           // degree of node lo+tid (if tid < nn)
  off[tid] = v;
  __syncthreads();
  for (int o = 1; o < 512; o <<= 1) {
    int t = (tid >= o) ? off[tid - o] : 0;
    __syncthreads();
    off[tid] += t;
    __syncthreads();
  }
  off[tid] -= v;               // exclusive
  cur[tid] = off[tid];
  if (tid < nn) rowptr[lo + tid] = bb + off[tid];

  // ---- bucket-local degree counting sort -> order[lo..hi) (LDS atomics only)
  if (tid < DBINS) dh[tid] = 0;
  __syncthreads();
  int deg = (tid < nn) ? (v > 63 ? 63 : v) : -1;
  if (deg >= 0) atomicAdd(&dh[deg], 1);
  __syncthreads();
  if (tid < DBINS) scn[tid] = dh[tid];   // scn free after bucket-base scan
  __syncthreads();
  for (int o = 1; o < DBINS; o <<= 1) {
    int t = (tid >= o && tid < DBINS) ? scn[tid - o] : 0;
    __syncthreads();
    if (tid < DBINS) scn[tid] += t;
    __syncthreads();
  }
  if (tid < DBINS) dh[tid] = scn[tid] - dh[tid];   // exclusive base -> cursor
  __syncthreads();
  if (deg >= 0) {
    int slot = atomicAdd(&dh[deg], 1);
    order[lo + slot] = lo + tid;
  }

  // ---- csr scatter ----
  for (int i = tid; i < ne; i += 512) {
    int d = (int)pb2[i].x - lo;
    int slot = atomicAdd(&cur[d], 1);
    csr[bb + slot] = (int)pb2[i].y;
  }
}

// ---------------- fused mean-aggregate + GEMM, degree-sorted tiles ----------
// r10-identical kernel (measured ~80us/layer by decomposition): r6 structure
// (44 VGPR, no spill) + order[] indirection so each block's 32 nodes are
// degree-adjacent -> barrier waits ~mean degree, not E[max32 Poi16] = 1.55x.

#define ACC8(v)                                          \
  acc[0] += bflo(v.x); acc[1] += bfhi(v.x);              \
  acc[2] += bflo(v.y); acc[3] += bfhi(v.y);              \
  acc[4] += bflo(v.z); acc[5] += bfhi(v.z);              \
  acc[6] += bflo(v.w); acc[7] += bfhi(v.w);

__global__ __launch_bounds__(512, 4) void k_fused(
    const unsigned short* __restrict__ table,   // gather table AND x-half rows
    const int* __restrict__ rowptr, const int* __restrict__ csr,
    const int* __restrict__ order,
    const unsigned short* __restrict__ Wp, const float* __restrict__ bias,
    void* __restrict__ outp, int relu_bf16_out) {
  __shared__ unsigned short meanB[QTILE * 128];   // 8 KB, XOR-swizzled 16B groups
  int tid = threadIdx.x;
  int g = tid >> 4;          // node slot 0..31 within tile
  int l = tid & 15;          // 16B lane within row
  int n0 = blockIdx.x * QTILE;
  int node = order[n0 + g];  // degree-sorted indirection (uniform per group)

  // ---- phase 1: mean of in-neighbors (r4/r6 exact inner loop) ----
  int beg = rowptr[node], end = rowptr[node + 1];
  float acc[8] = {0.f, 0.f, 0.f, 0.f, 0.f, 0.f, 0.f, 0.f};
  int e = beg;
  for (; e + 8 <= end; e += 8) {     // 8 gathers in flight
    int s0 = csr[e], s1 = csr[e + 1], s2 = csr[e + 2], s3 = csr[e + 3];
    int s4 = csr[e + 4], s5 = csr[e + 5], s6 = csr[e + 6], s7 = csr[e + 7];
    uint4 v0 = *reinterpret_cast<const uint4*>(table + (size_t)s0 * D + l * 8);
    uint4 v1 = *reinterpret_cast<const uint4*>(table + (size_t)s1 * D + l * 8);
    uint4 v2 = *reinterpret_cast<const uint4*>(table + (size_t)s2 * D + l * 8);
    uint4 v3 = *reinterpret_cast<const uint4*>(table + (size_t)s3 * D + l * 8);
    uint4 v4 = *reinterpret_cast<const uint4*>(table + (size_t)s4 * D + l * 8);
    uint4 v5 = *reinterpret_cast<const uint4*>(table + (size_t)s5 * D + l * 8);
    uint4 v6 = *reinterpret_cast<const uint4*>(table + (size_t)s6 * D + l * 8);
    uint4 v7 = *reinterpret_cast<const uint4*>(table + (size_t)s7 * D + l * 8);
    ACC8(v0) ACC8(v1) ACC8(v2) ACC8(v3)
    ACC8(v4) ACC8(v5) ACC8(v6) ACC8(v7)
  }
  for (; e + 4 <= end; e += 4) {
    int s0 = csr[e], s1 = csr[e + 1], s2 = csr[e + 2], s3 = csr[e + 3];
    uint4 v0 = *reinterpret_cast<const uint4*>(table + (size_t)s0 * D + l * 8);
    uint4 v1 = *reinterpret_cast<const uint4*>(table + (size_t)s1 * D + l * 8);
    uint4 v2 = *reinterpret_cast<const uint4*>(table + (size_t)s2 * D + l * 8);
    uint4 v3 = *reinterpret_cast<const uint4*>(table + (size_t)s3 * D + l * 8);
    ACC8(v0) ACC8(v1) ACC8(v2) ACC8(v3)
  }
  for (; e < end; ++e) {
    int s0 = csr[e];
    uint4 v0 = *reinterpret_cast<const uint4*>(table + (size_t)s0 * D + l * 8);
    ACC8(v0)
  }
  float inv = (end > beg) ? 1.0f / (float)(end - beg) : 0.0f;
  uint4 o;
  o.x = (uint32)f2bf(acc[0] * inv) | ((uint32)f2bf(acc[1] * inv) << 16);
  o.y = (uint32)f2bf(acc[2] * inv) | ((uint32)f2bf(acc[3] * inv) << 16);
  o.z = (uint32)f2bf(acc[4] * inv) | ((uint32)f2bf(acc[5] * inv) << 16);
  o.w = (uint32)f2bf(acc[6] * inv) | ((uint32)f2bf(acc[7] * inv) << 16);
  // swizzled store: content-group l -> slot l^(g&15)  (bank-spread reads)
  *reinterpret_cast<uint4*>(&meanB[g * 128 + (l ^ (g & 15)) * 8]) = o;
  __syncthreads();

  // ---- phase 2: [mean | x] @ Wp (r6's verified mapping; rows via order[]) ----
  int wave = tid >> 6;       // 8 waves: wr = row-half, wc = col-quarter
  int lane = tid & 63;
  int wr = wave >> 2;
  int wc = wave & 3;
  int q = lane >> 4;
  int r = lane & 15;

  short8 Bf[8][2];           // registers live only in phase 2
  const unsigned short* wp = Wp + (size_t)wc * 8192 + lane * 8;
#pragma unroll
  for (int ks = 0; ks < 8; ++ks)
#pragma unroll
    for (int t = 0; t < 2; ++t)
      Bf[ks][t] = *reinterpret_cast<const short8*>(wp + (ks * 2 + t) * 512);

  int arow = wr * 16 + r;    // A row slot within tile
  int an = order[n0 + arow]; // its node id
  short8 A[8];
  const unsigned short* ax = table + (size_t)an * D + q * 8;
#pragma unroll
  for (int ks = 0; ks < 4; ++ks)
    A[4 + ks] = *reinterpret_cast<const short8*>(ax + ks * 32);
#pragma unroll
  for (int ks = 0; ks < 4; ++ks) {   // mean half: slot = group ^ (row&15)
    int slot = (ks * 4 + q) ^ r;
    A[ks] = *reinterpret_cast<const short8*>(&meanB[arow * 128 + slot * 8]);
  }

  f32x4 c0 = {0.f, 0.f, 0.f, 0.f}, c1 = {0.f, 0.f, 0.f, 0.f};
#pragma unroll
  for (int ks = 0; ks < 8; ++ks) {
    c0 = __builtin_amdgcn_mfma_f32_16x16x32_bf16(A[ks], Bf[ks][0], c0, 0, 0, 0);
    c1 = __builtin_amdgcn_mfma_f32_16x16x32_bf16(A[ks], Bf[ks][1], c1, 0, 0, 0);
  }

  float bia0 = bias[wc * 32 + r];
  float bia1 = bias[wc * 32 + 16 + r];
  // C: col=lane&15, row(slot)=wr*16+q*4+gg -> node order[n0+slot] (row scatter)
  if (relu_bf16_out) {
#pragma unroll
    for (int gg = 0; gg < 4; ++gg) {
      int on = order[n0 + wr * 16 + q * 4 + gg];
      unsigned short* ob = (unsigned short*)outp + (size_t)on * D + wc * 32 + r;
      ob[0] = f2bf(fmaxf(c0[gg] + bia0, 0.f));
      ob[16] = f2bf(fmaxf(c1[gg] + bia1, 0.f));
    }
  } else {
#pragma unroll
    for (int gg = 0; gg < 4; ++gg) {
      int on = order[n0 + wr * 16 + q * 4 + gg];
      float* of = (float*)outp + (size_t)on * D + wc * 32 + r;
      of[0] = c0[gg] + bia0;
      of[16] = c1[gg] + bia1;
    }
  }
}

// ---------------- launch ----------------

extern "C" void kernel_launch(void* const* d_in, const int* in_sizes, int n_in,
                              void* d_out, int out_size, void* d_ws, size_t ws_size,
                              hipStream_t stream) {
  const float* x   = (const float*)d_in[0];
  const int*   ei  = (const int*)d_in[1];
  const float* Wl1 = (const float*)d_in[2];
  const float* Wr1 = (const float*)d_in[3];
  const float* b1  = (const float*)d_in[4];
  const float* Wl2 = (const float*)d_in[5];
  const float* Wr2 = (const float*)d_in[6];
  const float* b2  = (const float*)d_in[7];
  float* out = (float*)d_out;

  const int* esrc = ei;
  const int* edst = ei + N_EDGES;

  char* p = (char*)d_ws;
  auto take = [&](size_t bytes) {
    char* q = p;
    p += (bytes + 255) & ~(size_t)255;
    return q;
  };
  int* bcnt   = (int*)take(256 * 4);
  int* rowptr = (int*)take((size_t)(N_NODES + 1) * 4);
  int* csr    = (int*)take((size_t)N_EDGES * 4);
  int* order  = (int*)take((size_t)N_NODES * 4);
  uint2* pairs = (uint2*)take((size_t)NBUCK * BSTRIDE * 8);   // 14.5 MB
  unsigned short* xb  = (unsigned short*)take((size_t)N_NODES * D * 2);
  unsigned short* hb  = (unsigned short*)take((size_t)N_NODES * D * 2);
  unsigned short* Wp1 = (unsigned short*)take(256 * 128 * 2);
  unsigned short* Wp2 = (unsigned short*)take(256 * 128 * 2);

  const int npart = (N_EDGES + PCHUNK - 1) / PCHUNK;   // 782

  // CSR build: partition -> (per-bucket rowptr+csr+order || prep on idle CUs)
  hipMemsetAsync(bcnt, 0, 256 * 4, stream);
  k_part<<<npart, 256, 0, stream>>>(esrc, edst, bcnt, pairs);
  k_csr_prep<<<NBUCK + CASTB + WPACKB, 512, 0, stream>>>(
      pairs, bcnt, rowptr, csr, order, x, xb, Wl1, Wr1, Wl2, Wr2, Wp1, Wp2);

  // layer 1: hb = relu([mean(xb)|xb] @ Wp1 + b1)   (bf16 out)
  k_fused<<<NTILE, 512, 0, stream>>>(xb, rowptr, csr, order, Wp1, b1, hb, 1);
  // layer 2: out = [mean(hb)|hb] @ Wp2 + b2        (f32 out)
  k_fused<<<NTILE, 512, 0, stream>>>(hb, rowptr, csr, order, Wp2, b2, out, 0);
}

// Round 12
// 309.836 us; speedup vs baseline: 1.8362x; 1.0641x over previous
//
#include <hip/hip_runtime.h>
#include <stdint.h>

#define N_NODES 100000
#define N_EDGES 1600000
#define D 128
#define NBUCK 196          // ceil(N_NODES/512); bucket b = dst >> 9
#define BSTRIDE 9216       // padded csr region per bucket (mean 8192, +11 sigma)
#define PCHUNK 2048        // edges per k_part block
#define NCHUNK 782         // ceil(N_EDGES / PCHUNK)
#define CAP 48             // per-(bucket,chunk) cell capacity (mean 10.5, P(>=48)~1e-16)
#define QTILE 32           // nodes per fused block
#define NTILE (N_NODES / QTILE)   // 3125 exact
#define CASTB 3125         // 512-thread cast blocks: 3125*512*8 = 12.8M floats exact
#define WPACKB 128         // 128*512 = 65536 weight elements (both layers)

typedef unsigned int uint32;
typedef __attribute__((ext_vector_type(8))) short short8;   // 8 bf16 = 4 VGPRs
typedef __attribute__((ext_vector_type(4))) float f32x4;

__device__ __forceinline__ unsigned short f2bf(float f) {
  unsigned u = __builtin_bit_cast(unsigned, f);
  u += 0x7fffu + ((u >> 16) & 1u);          // round-to-nearest-even
  return (unsigned short)(u >> 16);
}
__device__ __forceinline__ float bflo(unsigned v) {
  return __builtin_bit_cast(float, v << 16);
}
__device__ __forceinline__ float bfhi(unsigned v) {
  return __builtin_bit_cast(float, v & 0xffff0000u);
}

// ---------------- CSR build, ZERO global atomics ----------------
// Lessons enforced here:
//  r3: no per-edge global atomic scatter (15x write amplification).
//  r10: no contended global atomic counters (lines ping-pong across XCDs).
//  r11(new): k_part's bcnt reservation was 153K global atomics on 16 lines
//  -> replaced by deterministic per-(bucket,chunk) cells + count rows.

// Each chunk LDS-sorts its 2048 edges by dst-bucket and writes bucket-b run
// to fixed cell gpairs[(b*NCHUNK+c)*CAP .. +CAP), packed (dloc<<17)|src
// (src < 2^17, dloc = dst&511 < 2^9). Count row written coalesced, no atomics.
__global__ __launch_bounds__(256) void k_part(const int* __restrict__ src,
                                              const int* __restrict__ dst,
                                              uint32* __restrict__ gpairs,
                                              int* __restrict__ counts) {
  __shared__ uint32 pk[PCHUNK];                       // 8 KB packed entries
  __shared__ uint32 srt[PCHUNK];                      // 8 KB bucket-sorted
  __shared__ unsigned short bk[PCHUNK], bkk[PCHUNK];  // 4+4 KB bucket ids
  __shared__ int hist[256], stmp[256], loff[256], cpos[256];
  int tid = threadIdx.x;
  int c = blockIdx.x;
  int e0 = c * PCHUNK;
  int nv = N_EDGES - e0;
  if (nv > PCHUNK) nv = PCHUNK;

  hist[tid] = 0;
  __syncthreads();
  for (int i = tid; i < nv; i += 256) {
    int d = dst[e0 + i];
    int s = src[e0 + i];
    pk[i] = ((uint32)(d & 511) << 17) | (uint32)s;
    int b = d >> 9;
    bk[i] = (unsigned short)b;
    atomicAdd(&hist[b], 1);         // LDS only
  }
  __syncthreads();
  int v = hist[tid];
  stmp[tid] = v;
  __syncthreads();
  for (int off = 1; off < 256; off <<= 1) {
    int t = (tid >= off) ? stmp[tid - off] : 0;
    __syncthreads();
    stmp[tid] += t;
    __syncthreads();
  }
  loff[tid] = stmp[tid] - v;
  cpos[tid] = stmp[tid] - v;
  __syncthreads();
  for (int i = tid; i < nv; i += 256) {
    int b = bk[i];
    int r = atomicAdd(&cpos[b], 1);  // LDS only
    srt[r] = pk[i];
    bkk[r] = (unsigned short)b;
  }
  __syncthreads();
  for (int i = tid; i < nv; i += 256) {   // coalesced runs per bucket cell
    int b = bkk[i];
    int j = i - loff[b];
    if (j < CAP)
      gpairs[((size_t)b * NCHUNK + c) * CAP + j] = srt[i];
  }
  if (tid < NBUCK)
    counts[(size_t)c * NBUCK + tid] = (hist[tid] < CAP) ? hist[tid] : CAP;
}

// Merged dispatch: blocks [0,NBUCK) assemble bucket-padded CSR from cells
// (rowbe[n] = (beg,end) absolute into csr; bucket base = b*BSTRIDE, so no
// cross-bucket scan and no global bcnt). Remaining 3253 blocks do x-cast +
// W-pack on the CUs the 196 csr blocks leave idle.
__global__ __launch_bounds__(512) void k_csr_prep(
    const uint32* __restrict__ gpairs, const int* __restrict__ counts,
    int2* __restrict__ rowbe, int* __restrict__ csr,
    const float* __restrict__ x, unsigned short* __restrict__ xb,
    const float* __restrict__ Wl1, const float* __restrict__ Wr1,
    const float* __restrict__ Wl2, const float* __restrict__ Wr2,
    unsigned short* __restrict__ Wp1, unsigned short* __restrict__ Wp2) {
  __shared__ int cellcnt[NCHUNK];    // 3.1 KB
  __shared__ int cellbase[NCHUNK];   // 3.1 KB
  __shared__ int ebuf[BSTRIDE];      // 36.9 KB packed entries of this bucket
  __shared__ int hist[512], off[512], cur[512];   // 6 KB
  __shared__ int neS;
  int tid = threadIdx.x;
  int blk = blockIdx.x;

  if (blk >= NBUCK) {
    int pb = blk - NBUCK;
    if (pb < CASTB) {                     // x f32 -> bf16, 8 elems/thread
      size_t i = (size_t)pb * 512 + tid;  // < 1.6M exact
      float4 a = *reinterpret_cast<const float4*>(x + i * 8);
      float4 c2 = *reinterpret_cast<const float4*>(x + i * 8 + 4);
      uint4 o;
      o.x = (uint32)f2bf(a.x) | ((uint32)f2bf(a.y) << 16);
      o.y = (uint32)f2bf(a.z) | ((uint32)f2bf(a.w) << 16);
      o.z = (uint32)f2bf(c2.x) | ((uint32)f2bf(c2.y) << 16);
      o.w = (uint32)f2bf(c2.z) | ((uint32)f2bf(c2.w) << 16);
      *reinterpret_cast<uint4*>(xb + i * 8) = o;
    } else {                              // pack both layers' W into B-frag order
      int t = (pb - CASTB) * 512 + tid;   // < 65536 exact
      int which = t >> 15;
      int tt = t & 32767;
      int j = tt & 7;
      int lane = (tt >> 3) & 63;
      int tile = (tt >> 9) & 1;
      int ks = (tt >> 10) & 7;
      int ng = (tt >> 13) & 3;
      int k = ks * 32 + (lane >> 4) * 8 + j;
      int n = ng * 32 + tile * 16 + (lane & 15);
      const float* Wl = which ? Wl2 : Wl1;
      const float* Wr = which ? Wr2 : Wr1;
      float w = (k < 128) ? Wl[k * 128 + n] : Wr[(k - 128) * 128 + n];
      (which ? Wp2 : Wp1)[tt] = f2bf(w);
    }
    return;
  }

  int b = blk;
  int lo = b << 9;
  int hi = lo + 512;
  if (hi > N_NODES) hi = N_NODES;
  int nn = hi - lo;            // 512 or 160

  for (int cc = tid; cc < NCHUNK; cc += 512)
    cellcnt[cc] = counts[(size_t)cc * NBUCK + b];
  hist[tid] = 0;
  __syncthreads();
  if (tid == 0) {              // serial cell scan (~3us, concurrent across blocks)
    int run = 0;
    for (int cc = 0; cc < NCHUNK; ++cc) { cellbase[cc] = run; run += cellcnt[cc]; }
    neS = (run > BSTRIDE) ? BSTRIDE : run;
  }
  __syncthreads();

  // gather cells into LDS + per-node degree hist
  for (int cc = tid; cc < NCHUNK; cc += 512) {
    int cb = cellbase[cc];
    int n = cellcnt[cc];
    if (cb + n > BSTRIDE) n = (BSTRIDE - cb > 0) ? (BSTRIDE - cb) : 0;
    const uint32* gp = gpairs + ((size_t)b * NCHUNK + cc) * CAP;
    for (int j = 0; j < n; ++j) {
      uint32 e = gp[j];
      ebuf[cb + j] = (int)e;
      atomicAdd(&hist[e >> 17], 1);   // LDS only
    }
  }
  __syncthreads();
  int ne = neS;
  int v = hist[tid];
  off[tid] = v;
  __syncthreads();
  for (int o = 1; o < 512; o <<= 1) {
    int t = (tid >= o) ? off[tid - o] : 0;
    __syncthreads();
    off[tid] += t;
    __syncthreads();
  }
  off[tid] -= v;               // exclusive
  cur[tid] = off[tid];
  int bb = b * BSTRIDE;
  if (tid < nn) rowbe[lo + tid] = make_int2(bb + off[tid], bb + off[tid] + v);
  __syncthreads();
  for (int i = tid; i < ne; i += 512) {
    uint32 e = (uint32)ebuf[i];
    int dl = (int)(e >> 17);
    int slot = atomicAdd(&cur[dl], 1);   // LDS only
    csr[bb + slot] = (int)(e & 0x1FFFFu);
  }
}

// ---------------- fused mean-aggregate + GEMM (r6-exact, best verified) ----
// 88.5us/layer measured. Gather loop = proven branch-free 8-deep pipeline.
// Only change vs r6: single int2 rowbe load replaces two rowptr loads.
// r0/r7/r9/r11 lessons: no segmentation, no stealing queue, no order[]
// indirection in this kernel — every variant regressed.

#define ACC8(v)                                          \
  acc[0] += bflo(v.x); acc[1] += bfhi(v.x);              \
  acc[2] += bflo(v.y); acc[3] += bfhi(v.y);              \
  acc[4] += bflo(v.z); acc[5] += bfhi(v.z);              \
  acc[6] += bflo(v.w); acc[7] += bfhi(v.w);

__global__ __launch_bounds__(512, 4) void k_fused(
    const unsigned short* __restrict__ table,   // gather table AND x-half rows
    const int2* __restrict__ rowbe, const int* __restrict__ csr,
    const unsigned short* __restrict__ Wp, const float* __restrict__ bias,
    void* __restrict__ outp, int relu_bf16_out) {
  __shared__ unsigned short meanB[QTILE * 128];   // 8 KB, XOR-swizzled 16B groups
  int tid = threadIdx.x;
  int g = tid >> 4;          // node 0..31 within tile
  int l = tid & 15;          // 16B lane within row
  int tile = blockIdx.x;     // grid = NTILE exact
  int n0 = tile * QTILE;
  int node = n0 + g;

  // ---- phase 1: mean of in-neighbors ----
  int2 be = rowbe[node];
  int beg = be.x, end = be.y;
  float acc[8] = {0.f, 0.f, 0.f, 0.f, 0.f, 0.f, 0.f, 0.f};
  int e = beg;
  for (; e + 8 <= end; e += 8) {     // 8 gathers in flight
    int s0 = csr[e], s1 = csr[e + 1], s2 = csr[e + 2], s3 = csr[e + 3];
    int s4 = csr[e + 4], s5 = csr[e + 5], s6 = csr[e + 6], s7 = csr[e + 7];
    uint4 v0 = *reinterpret_cast<const uint4*>(table + (size_t)s0 * D + l * 8);
    uint4 v1 = *reinterpret_cast<const uint4*>(table + (size_t)s1 * D + l * 8);
    uint4 v2 = *reinterpret_cast<const uint4*>(table + (size_t)s2 * D + l * 8);
    uint4 v3 = *reinterpret_cast<const uint4*>(table + (size_t)s3 * D + l * 8);
    uint4 v4 = *reinterpret_cast<const uint4*>(table + (size_t)s4 * D + l * 8);
    uint4 v5 = *reinterpret_cast<const uint4*>(table + (size_t)s5 * D + l * 8);
    uint4 v6 = *reinterpret_cast<const uint4*>(table + (size_t)s6 * D + l * 8);
    uint4 v7 = *reinterpret_cast<const uint4*>(table + (size_t)s7 * D + l * 8);
    ACC8(v0) ACC8(v1) ACC8(v2) ACC8(v3)
    ACC8(v4) ACC8(v5) ACC8(v6) ACC8(v7)
  }
  for (; e + 4 <= end; e += 4) {
    int s0 = csr[e], s1 = csr[e + 1], s2 = csr[e + 2], s3 = csr[e + 3];
    uint4 v0 = *reinterpret_cast<const uint4*>(table + (size_t)s0 * D + l * 8);
    uint4 v1 = *reinterpret_cast<const uint4*>(table + (size_t)s1 * D + l * 8);
    uint4 v2 = *reinterpret_cast<const uint4*>(table + (size_t)s2 * D + l * 8);
    uint4 v3 = *reinterpret_cast<const uint4*>(table + (size_t)s3 * D + l * 8);
    ACC8(v0) ACC8(v1) ACC8(v2) ACC8(v3)
  }
  for (; e < end; ++e) {
    int s0 = csr[e];
    uint4 v0 = *reinterpret_cast<const uint4*>(table + (size_t)s0 * D + l * 8);
    ACC8(v0)
  }
  float inv = (end > beg) ? 1.0f / (float)(end - beg) : 0.0f;
  uint4 o;
  o.x = (uint32)f2bf(acc[0] * inv) | ((uint32)f2bf(acc[1] * inv) << 16);
  o.y = (uint32)f2bf(acc[2] * inv) | ((uint32)f2bf(acc[3] * inv) << 16);
  o.z = (uint32)f2bf(acc[4] * inv) | ((uint32)f2bf(acc[5] * inv) << 16);
  o.w = (uint32)f2bf(acc[6] * inv) | ((uint32)f2bf(acc[7] * inv) << 16);
  // swizzled store: content-group l -> slot l^(g&15)  (bank-spread reads)
  *reinterpret_cast<uint4*>(&meanB[g * 128 + (l ^ (g & 15)) * 8]) = o;
  __syncthreads();

  // ---- phase 2: [mean | x] @ Wp (r6's verified mapping) ----
  int wave = tid >> 6;       // 8 waves: wr = row-half, wc = col-quarter
  int lane = tid & 63;
  int wr = wave >> 2;
  int wc = wave & 3;
  int q = lane >> 4;
  int r = lane & 15;

  short8 Bf[8][2];           // registers live only in phase 2
  const unsigned short* wp = Wp + (size_t)wc * 8192 + lane * 8;
#pragma unroll
  for (int ks = 0; ks < 8; ++ks)
#pragma unroll
    for (int t = 0; t < 2; ++t)
      Bf[ks][t] = *reinterpret_cast<const short8*>(wp + (ks * 2 + t) * 512);

  int arow = wr * 16 + r;    // A row within tile
  short8 A[8];
  const unsigned short* ax = table + (size_t)(n0 + arow) * D + q * 8;
#pragma unroll
  for (int ks = 0; ks < 4; ++ks)
    A[4 + ks] = *reinterpret_cast<const short8*>(ax + ks * 32);
#pragma unroll
  for (int ks = 0; ks < 4; ++ks) {   // mean half: slot = group ^ (row&15)
    int slot = (ks * 4 + q) ^ r;
    A[ks] = *reinterpret_cast<const short8*>(&meanB[arow * 128 + slot * 8]);
  }

  f32x4 c0 = {0.f, 0.f, 0.f, 0.f}, c1 = {0.f, 0.f, 0.f, 0.f};
#pragma unroll
  for (int ks = 0; ks < 8; ++ks) {
    c0 = __builtin_amdgcn_mfma_f32_16x16x32_bf16(A[ks], Bf[ks][0], c0, 0, 0, 0);
    c1 = __builtin_amdgcn_mfma_f32_16x16x32_bf16(A[ks], Bf[ks][1], c1, 0, 0, 0);
  }

  float bia0 = bias[wc * 32 + r];
  float bia1 = bias[wc * 32 + 16 + r];
  int orow = n0 + wr * 16 + q * 4;   // C: col=lane&15, row=quad*4+reg
  if (relu_bf16_out) {
    unsigned short* ob = (unsigned short*)outp + (size_t)orow * D + wc * 32 + r;
#pragma unroll
    for (int gg = 0; gg < 4; ++gg) {
      ob[(size_t)gg * D] = f2bf(fmaxf(c0[gg] + bia0, 0.f));
      ob[(size_t)gg * D + 16] = f2bf(fmaxf(c1[gg] + bia1, 0.f));
    }
  } else {
    float* of = (float*)outp + (size_t)orow * D + wc * 32 + r;
#pragma unroll
    for (int gg = 0; gg < 4; ++gg) {
      of[(size_t)gg * D] = c0[gg] + bia0;
      of[(size_t)gg * D + 16] = c1[gg] + bia1;
    }
  }
}

// ---------------- launch ----------------

extern "C" void kernel_launch(void* const* d_in, const int* in_sizes, int n_in,
                              void* d_out, int out_size, void* d_ws, size_t ws_size,
                              hipStream_t stream) {
  const float* x   = (const float*)d_in[0];
  const int*   ei  = (const int*)d_in[1];
  const float* Wl1 = (const float*)d_in[2];
  const float* Wr1 = (const float*)d_in[3];
  const float* b1  = (const float*)d_in[4];
  const float* Wl2 = (const float*)d_in[5];
  const float* Wr2 = (const float*)d_in[6];
  const float* b2  = (const float*)d_in[7];
  float* out = (float*)d_out;

  const int* esrc = ei;
  const int* edst = ei + N_EDGES;

  char* p = (char*)d_ws;
  auto take = [&](size_t bytes) {
    char* q = p;
    p += (bytes + 255) & ~(size_t)255;
    return q;
  };
  int2* rowbe = (int2*)take((size_t)N_NODES * 8);                    // 800 KB
  int* csr    = (int*)take((size_t)NBUCK * BSTRIDE * 4);             // 7.2 MB padded
  uint32* gpairs = (uint32*)take((size_t)NBUCK * NCHUNK * CAP * 4);  // 29.4 MB
  int* counts = (int*)take((size_t)NCHUNK * NBUCK * 4);              // 613 KB
  unsigned short* xb  = (unsigned short*)take((size_t)N_NODES * D * 2);
  unsigned short* hb  = (unsigned short*)take((size_t)N_NODES * D * 2);
  unsigned short* Wp1 = (unsigned short*)take(256 * 128 * 2);
  unsigned short* Wp2 = (unsigned short*)take(256 * 128 * 2);

  // CSR build: chunk-sort to deterministic cells (no atomics, no memset) ->
  // (per-bucket cell-merge rowbe+csr || prep on idle CUs)
  k_part<<<NCHUNK, 256, 0, stream>>>(esrc, edst, gpairs, counts);
  k_csr_prep<<<NBUCK + CASTB + WPACKB, 512, 0, stream>>>(
      gpairs, counts, rowbe, csr, x, xb, Wl1, Wr1, Wl2, Wr2, Wp1, Wp2);

  // layer 1: hb = relu([mean(xb)|xb] @ Wp1 + b1)   (bf16 out)
  k_fused<<<NTILE, 512, 0, stream>>>(xb, rowbe, csr, Wp1, b1, hb, 1);
  // layer 2: out = [mean(hb)|hb] @ Wp2 + b2        (f32 out)
  k_fused<<<NTILE, 512, 0, stream>>>(hb, rowbe, csr, Wp2, b2, out, 0);
}